// Round 16
// baseline (182.482 us; speedup 1.0000x reference)
//
#include <hip/hip_runtime.h>
#include <hip/hip_bf16.h>
#include <cstdint>
#include <cstddef>

#define S_LEN 2048
#define D_HEAD 64
#define NBH 32                      // B*H = 2*16
#define NELEM 4194304               // NBH * S_LEN * D_HEAD
#define RPITCH 264                  // padded LDS row pitch (bytes) for 128 bf16

typedef __attribute__((ext_vector_type(8))) short short8;
typedef __attribute__((ext_vector_type(4))) float f32x4;

__device__ __forceinline__ short f2bf(float f) {
    union { float f; uint32_t u; } v; v.f = f;
    uint32_t u = v.u + 0x7FFFu + ((v.u >> 16) & 1u);   // RNE, inputs finite
    return (short)(u >> 16);
}

__device__ __forceinline__ uint32_t pkbf(float lo, float hi) {
    return ((uint32_t)(uint16_t)f2bf(hi) << 16) | (uint32_t)(uint16_t)f2bf(lo);
}

// K fp32 -> fragment-major bf16:
// Kf slot s = ((bh*128 + g)*2 + p)*64 + l holds K[bh][g*16 + (l&15)][p*32 + (l>>4)*8 + e]
__global__ void convert_kf_kernel(const float* __restrict__ K, short* __restrict__ Kf) {
    const int s = blockIdx.x * 256 + threadIdx.x;      // 524288 slots total
    const int l = s & 63;
    const int p = (s >> 6) & 1;
    const int g = (s >> 7) & 127;
    const int bh = s >> 14;
    const float* src = K + ((size_t)bh * S_LEN + g * 16 + (l & 15)) * D_HEAD
                         + p * 32 + (l >> 4) * 8;
    short8 y;
    #pragma unroll
    for (int e = 0; e < 8; ++e) y[e] = f2bf(src[e]);
    *reinterpret_cast<short8*>(Kf + (size_t)s * 8) = y;
}

// V fp32 [bh][S][D] -> fragment-major bf16:
// Vf slot s = ((bh*64 + t)*4 + vt)*64 + l holds V[bh][t*32 + (l>>4)*8 + e][vt*16 + (l&15)]
__global__ void transpose_vf_kernel(const float* __restrict__ V, short* __restrict__ Vf) {
    __shared__ float tile[64][65];
    const int bh = blockIdx.y;
    const int s0 = blockIdx.x * 64;
    const int d = threadIdx.x & 63;
    const int r = threadIdx.x >> 6;
    const float* vp = V + ((size_t)bh * S_LEN + s0) * D_HEAD;
    #pragma unroll
    for (int i = 0; i < 16; ++i) {
        int srow = i * 4 + r;
        tile[srow][d] = vp[(size_t)srow * D_HEAD + d];
    }
    __syncthreads();
    #pragma unroll
    for (int h = 0; h < 2; ++h) {
        const int sl = h * 256 + threadIdx.x;          // 512 slots per block
        const int ti = sl >> 8;                        // j-subtile 0..1
        const int vt = (sl >> 6) & 3;
        const int l  = sl & 63;
        const int lrow = l & 15, lgrp = l >> 4;
        short8 y;
        #pragma unroll
        for (int e = 0; e < 8; ++e)
            y[e] = f2bf(tile[ti * 32 + lgrp * 8 + e][vt * 16 + lrow]);
        *reinterpret_cast<short8*>(
            Vf + ((((size_t)bh * 64 + (s0 >> 5) + ti) * 4 + vt) * 64 + l) * 8) = y;
    }
}

// Fused attention — occupancy experiment: wave = 16 q-rows (no subtile
// sharing; K re-reads are L2-resident via XCD swizzle), block = 4 waves =
// 64 rows, grid = 1024 blocks -> 3-4 blocks/CU (was grid-capped at 2).
// bf16-packed LDS stage (16.5 KB/block, padded rows), bounds(256,3).
// Pass-2 keeps R12's validated schedule: K prefetch issued BEFORE the
// nontemporal 512B-segment store bursts (counted-vmcnt decoupling).
__launch_bounds__(256, 3)
__global__ void attn_kernel(const float* __restrict__ Q,
                            const short* __restrict__ Kf,
                            const short* __restrict__ Vf,
                            float* __restrict__ Out,
                            float* __restrict__ P) {
    __shared__ __align__(16) unsigned short stage[4][16][RPITCH / 2];  // 16.5 KB

    const int lane = threadIdx.x & 63;
    const int w    = threadIdx.x >> 6;
    // XCD swizzle: b in [0,1024); bijective; 128 consecutive per XCD -> 4 bh
    const int b    = blockIdx.y * 32 + blockIdx.x;
    const int swzb = (b & 7) * 128 + (b >> 3);
    const int bx   = swzb & 31;
    const int bh   = swzb >> 5;
    const int qb   = bx * 64 + w * 16;                 // wave's 16-row base
    const int lrow = lane & 15;
    const int lgrp = lane >> 4;
    const float scale = 0.125f;                        // 1/sqrt(64)

    short8 qa0, qa1;
    {
        const float* qr = Q + ((size_t)bh * S_LEN + qb + lrow) * D_HEAD + lgrp * 8;
        #pragma unroll
        for (int e = 0; e < 8; ++e) qa0[e] = f2bf(qr[e]);
        #pragma unroll
        for (int e = 0; e < 8; ++e) qa1[e] = f2bf(qr[e + 32]);
    }

    const short* Kp = Kf + (size_t)bh * (S_LEN * D_HEAD);
    const short* Vp = Vf + (size_t)bh * (S_LEN * D_HEAD);
    const int lofs = lane * 8;

    const int srcA = ((lane & 15) + ((lane >> 4) & 1) * 32) << 2;
    const int srcB = srcA + (16 << 2);
    const bool glow = (lgrp < 2);

    // ---- pass 1: denominator + PV (unnormalized e) ----
    float l = 0.f;
    f32x4 acc[4] = {};
    for (int j0 = 0; j0 < S_LEN; j0 += 32) {
        const short* kg = Kp + (size_t)(j0 >> 4) * 1024;
        short8 k00 = *reinterpret_cast<const short8*>(kg + lofs);
        short8 k01 = *reinterpret_cast<const short8*>(kg + 512 + lofs);
        short8 k10 = *reinterpret_cast<const short8*>(kg + 1024 + lofs);
        short8 k11 = *reinterpret_cast<const short8*>(kg + 1536 + lofs);
        const short* vg = Vp + (size_t)(j0 >> 5) * 2048;
        short8 bv0 = *reinterpret_cast<const short8*>(vg + lofs);
        short8 bv1 = *reinterpret_cast<const short8*>(vg + 512 + lofs);
        short8 bv2 = *reinterpret_cast<const short8*>(vg + 1024 + lofs);
        short8 bv3 = *reinterpret_cast<const short8*>(vg + 1536 + lofs);

        f32x4 c0 = {0.f, 0.f, 0.f, 0.f};
        f32x4 c1 = {0.f, 0.f, 0.f, 0.f};
        c0 = __builtin_amdgcn_mfma_f32_16x16x32_bf16(k00, qa0, c0, 0, 0, 0);
        c0 = __builtin_amdgcn_mfma_f32_16x16x32_bf16(k01, qa1, c0, 0, 0, 0);
        c1 = __builtin_amdgcn_mfma_f32_16x16x32_bf16(k10, qa0, c1, 0, 0, 0);
        c1 = __builtin_amdgcn_mfma_f32_16x16x32_bf16(k11, qa1, c1, 0, 0, 0);
        float e0[4], e1[4];
        #pragma unroll
        for (int rr = 0; rr < 4; ++rr) {
            e0[rr] = __expf(c0[rr] * scale);
            e1[rr] = __expf(c1[rr] * scale);
            l += e0[rr] + e1[rr];
        }
        int w00 = (int)pkbf(e0[0], e0[1]);
        int w01 = (int)pkbf(e0[2], e0[3]);
        int w10 = (int)pkbf(e1[0], e1[1]);
        int w11 = (int)pkbf(e1[2], e1[3]);
        int t0 = __builtin_amdgcn_ds_bpermute(srcA, w00);
        int t1 = __builtin_amdgcn_ds_bpermute(srcA, w01);
        int t2 = __builtin_amdgcn_ds_bpermute(srcB, w00);
        int t3 = __builtin_amdgcn_ds_bpermute(srcB, w01);
        int u0 = __builtin_amdgcn_ds_bpermute(srcA, w10);
        int u1 = __builtin_amdgcn_ds_bpermute(srcA, w11);
        int u2 = __builtin_amdgcn_ds_bpermute(srcB, w10);
        int u3 = __builtin_amdgcn_ds_bpermute(srcB, w11);
        union { short8 s8; int wd[4]; } fr;
        fr.wd[0] = glow ? t0 : u0;
        fr.wd[1] = glow ? t1 : u1;
        fr.wd[2] = glow ? t2 : u2;
        fr.wd[3] = glow ? t3 : u3;
        acc[0] = __builtin_amdgcn_mfma_f32_16x16x32_bf16(fr.s8, bv0, acc[0], 0, 0, 0);
        acc[1] = __builtin_amdgcn_mfma_f32_16x16x32_bf16(fr.s8, bv1, acc[1], 0, 0, 0);
        acc[2] = __builtin_amdgcn_mfma_f32_16x16x32_bf16(fr.s8, bv2, acc[2], 0, 0, 0);
        acc[3] = __builtin_amdgcn_mfma_f32_16x16x32_bf16(fr.s8, bv3, acc[3], 0, 0, 0);
    }
    l += __shfl_xor(l, 16);
    l += __shfl_xor(l, 32);
    const float rl = 1.0f / l;                         // denom for q = qb+lrow

    // ---- Out epilogue (before the store-heavy pass 2) ----
    {
        float rlo[4];
        #pragma unroll
        for (int rr = 0; rr < 4; ++rr) rlo[rr] = __shfl(rl, lgrp * 4 + rr);
        float* ob = Out + ((size_t)bh * S_LEN + qb + lgrp * 4) * D_HEAD + lrow;
        #pragma unroll
        for (int vt = 0; vt < 4; ++vt) {
            #pragma unroll
            for (int rr = 0; rr < 4; ++rr)
                ob[(size_t)rr * D_HEAD + vt * 16] = acc[vt][rr] * rlo[rr];
        }
    }

    // ---- pass 2: P stream; bf16 stage (padded rows), prefetched K ----
    char* stg = (char*)&stage[w][0][0];
    float* Pb = P + (size_t)bh * S_LEN * S_LEN;

    short8 pk[4][4];                                   // next-superstep K frags
    #pragma unroll
    for (int jj = 0; jj < 4; ++jj) {
        const short* kg = Kp + (size_t)((jj * 32) >> 4) * 1024;
        pk[jj][0] = *reinterpret_cast<const short8*>(kg + lofs);
        pk[jj][1] = *reinterpret_cast<const short8*>(kg + 512 + lofs);
        pk[jj][2] = *reinterpret_cast<const short8*>(kg + 1024 + lofs);
        pk[jj][3] = *reinterpret_cast<const short8*>(kg + 1536 + lofs);
    }

    for (int sup = 0; sup < S_LEN; sup += 128) {
        // compute phase: consume prefetched K (oldest in vmcnt FIFO)
        #pragma unroll
        for (int jj = 0; jj < 4; ++jj) {
            short8 k00 = pk[jj][0], k01 = pk[jj][1], k10 = pk[jj][2], k11 = pk[jj][3];
            f32x4 c0 = {0.f, 0.f, 0.f, 0.f};
            f32x4 c1 = {0.f, 0.f, 0.f, 0.f};
            c0 = __builtin_amdgcn_mfma_f32_16x16x32_bf16(k00, qa0, c0, 0, 0, 0);
            c0 = __builtin_amdgcn_mfma_f32_16x16x32_bf16(k01, qa1, c0, 0, 0, 0);
            c1 = __builtin_amdgcn_mfma_f32_16x16x32_bf16(k10, qa0, c1, 0, 0, 0);
            c1 = __builtin_amdgcn_mfma_f32_16x16x32_bf16(k11, qa1, c1, 0, 0, 0);
            f32x4 p0, p1;
            #pragma unroll
            for (int rr = 0; rr < 4; ++rr) {
                p0[rr] = __expf(c0[rr] * scale) * rl;
                p1[rr] = __expf(c1[rr] * scale) * rl;
            }
            const int cb = (jj * 32 + lgrp * 4) << 1;  // byte offset in row
            *(uint2*)(stg + lrow * RPITCH + cb) =
                make_uint2(pkbf(p0[0], p0[1]), pkbf(p0[2], p0[3]));
            *(uint2*)(stg + lrow * RPITCH + cb + 32) =
                make_uint2(pkbf(p1[0], p1[1]), pkbf(p1[2], p1[3]));
        }

        asm volatile("s_waitcnt lgkmcnt(0)" ::: "memory");

        // prefetch next superstep's K BEFORE the store burst
        {
            const int nsup = (sup + 128 < S_LEN) ? (sup + 128) : 0;
            #pragma unroll
            for (int jj = 0; jj < 4; ++jj) {
                const short* kg = Kp + (size_t)((nsup + jj * 32) >> 4) * 1024;
                pk[jj][0] = *reinterpret_cast<const short8*>(kg + lofs);
                pk[jj][1] = *reinterpret_cast<const short8*>(kg + 512 + lofs);
                pk[jj][2] = *reinterpret_cast<const short8*>(kg + 1024 + lofs);
                pk[jj][3] = *reinterpret_cast<const short8*>(kg + 1536 + lofs);
            }
        }
        __builtin_amdgcn_sched_barrier(0);             // pin: loads stay above stores

        // drain: 2 rows x 512B per instruction (unpack bf16 -> f32), nt
        #pragma unroll
        for (int rb = 0; rb < 8; ++rb) {
            const int r = rb * 2 + (lane >> 5);
            const int c = lane & 31;
            uint2 v = *(const uint2*)(stg + r * RPITCH + c * 8);
            union { float f; uint32_t u; } e0, e1, e2, e3;
            e0.u = v.x << 16;  e1.u = v.x & 0xFFFF0000u;
            e2.u = v.y << 16;  e3.u = v.y & 0xFFFF0000u;
            f32x4 o = {e0.f, e1.f, e2.f, e3.f};
            __builtin_nontemporal_store(o,
                (f32x4*)(Pb + (size_t)(qb + r) * S_LEN + sup + c * 4));
        }
        asm volatile("s_waitcnt lgkmcnt(0)" ::: "memory");
    }
}

extern "C" void kernel_launch(void* const* d_in, const int* in_sizes, int n_in,
                              void* d_out, int out_size, void* d_ws, size_t ws_size,
                              hipStream_t stream) {
    const float* Q = (const float*)d_in[0];
    const float* K = (const float*)d_in[1];
    const float* V = (const float*)d_in[2];
    float* Out = (float*)d_out;
    float* P = Out + (size_t)NELEM;                    // outputs concatenated flat
    short* Kf = (short*)d_ws;                          // 8.4 MB
    short* Vf = Kf + (size_t)NELEM;                    // 8.4 MB (needs ws >= 16.8 MB)

    convert_kf_kernel<<<NELEM / (256 * 8), 256, 0, stream>>>(K, Kf);
    transpose_vf_kernel<<<dim3(S_LEN / 64, NBH), 256, 0, stream>>>(V, Vf);
    attn_kernel<<<dim3(S_LEN / 64, NBH), 256, 0, stream>>>(Q, Kf, Vf, Out, P);
}

// Round 17
// 174.999 us; speedup vs baseline: 1.0428x; 1.0428x over previous
//
#include <hip/hip_runtime.h>
#include <hip/hip_bf16.h>
#include <cstdint>
#include <cstddef>

#define S_LEN 2048
#define D_HEAD 64
#define NBH 32                      // B*H = 2*16
#define NELEM 4194304               // NBH * S_LEN * D_HEAD
#define SUP 128                     // columns per store superblock

typedef __attribute__((ext_vector_type(8))) short short8;
typedef __attribute__((ext_vector_type(4))) float f32x4;

__device__ __forceinline__ short f2bf(float f) {
    union { float f; uint32_t u; } v; v.f = f;
    uint32_t u = v.u + 0x7FFFu + ((v.u >> 16) & 1u);   // RNE, inputs finite
    return (short)(u >> 16);
}

__device__ __forceinline__ uint32_t pkbf(float lo, float hi) {
    return ((uint32_t)(uint16_t)f2bf(hi) << 16) | (uint32_t)(uint16_t)f2bf(lo);
}

// K fp32 -> fragment-major bf16:
// Kf slot s = ((bh*128 + g)*2 + p)*64 + l holds K[bh][g*16 + (l&15)][p*32 + (l>>4)*8 + e]
__global__ void convert_kf_kernel(const float* __restrict__ K, short* __restrict__ Kf) {
    const int s = blockIdx.x * 256 + threadIdx.x;      // 524288 slots total
    const int l = s & 63;
    const int p = (s >> 6) & 1;
    const int g = (s >> 7) & 127;
    const int bh = s >> 14;
    const float* src = K + ((size_t)bh * S_LEN + g * 16 + (l & 15)) * D_HEAD
                         + p * 32 + (l >> 4) * 8;
    short8 y;
    #pragma unroll
    for (int e = 0; e < 8; ++e) y[e] = f2bf(src[e]);
    *reinterpret_cast<short8*>(Kf + (size_t)s * 8) = y;
}

// V fp32 [bh][S][D] -> fragment-major bf16:
// Vf slot s = ((bh*64 + t)*4 + vt)*64 + l holds V[bh][t*32 + (l>>4)*8 + e][vt*16 + (l&15)]
__global__ void transpose_vf_kernel(const float* __restrict__ V, short* __restrict__ Vf) {
    __shared__ float tile[64][65];
    const int bh = blockIdx.y;
    const int s0 = blockIdx.x * 64;
    const int d = threadIdx.x & 63;
    const int r = threadIdx.x >> 6;
    const float* vp = V + ((size_t)bh * S_LEN + s0) * D_HEAD;
    #pragma unroll
    for (int i = 0; i < 16; ++i) {
        int srow = i * 4 + r;
        tile[srow][d] = vp[(size_t)srow * D_HEAD + d];
    }
    __syncthreads();
    #pragma unroll
    for (int h = 0; h < 2; ++h) {
        const int sl = h * 256 + threadIdx.x;          // 512 slots per block
        const int ti = sl >> 8;                        // j-subtile 0..1
        const int vt = (sl >> 6) & 3;
        const int l  = sl & 63;
        const int lrow = l & 15, lgrp = l >> 4;
        short8 y;
        #pragma unroll
        for (int e = 0; e < 8; ++e)
            y[e] = f2bf(tile[ti * 32 + lgrp * 8 + e][vt * 16 + lrow]);
        *reinterpret_cast<short8*>(
            Vf + ((((size_t)bh * 64 + (s0 >> 5) + ti) * 4 + vt) * 64 + l) * 8) = y;
    }
}

// Fused attention (best configuration, R12): wave = 32 q-rows (2 subtiles
// sharing K/V regs), fragment-major K/V loads, XCD-aware block swizzle,
// counted-vmcnt K prefetch issued BEFORE the nontemporal burst P stores.
__launch_bounds__(256, 2)
__global__ void attn_kernel(const float* __restrict__ Q,
                            const short* __restrict__ Kf,
                            const short* __restrict__ Vf,
                            float* __restrict__ Out,
                            float* __restrict__ P) {
    __shared__ __align__(16) float stage[4][2][16][SUP];   // 64 KB

    const int lane = threadIdx.x & 63;
    const int w    = threadIdx.x >> 6;
    // XCD swizzle: b = dispatch-linear id; swz bijective on [0,512)
    const int b    = blockIdx.y * 16 + blockIdx.x;
    const int swzb = (b & 7) * 64 + (b >> 3);
    const int bx   = swzb & 15;
    const int bh   = swzb >> 4;
    const int qb   = bx * 128 + w * 32;                // wave's 32-row base
    const int lrow = lane & 15;
    const int lgrp = lane >> 4;
    const float scale = 0.125f;                        // 1/sqrt(64)

    short8 qa0A, qa1A, qa0B, qa1B;
    {
        const float* qrA = Q + ((size_t)bh * S_LEN + qb + lrow) * D_HEAD + lgrp * 8;
        const float* qrB = qrA + 16 * D_HEAD;
        #pragma unroll
        for (int e = 0; e < 8; ++e) qa0A[e] = f2bf(qrA[e]);
        #pragma unroll
        for (int e = 0; e < 8; ++e) qa1A[e] = f2bf(qrA[e + 32]);
        #pragma unroll
        for (int e = 0; e < 8; ++e) qa0B[e] = f2bf(qrB[e]);
        #pragma unroll
        for (int e = 0; e < 8; ++e) qa1B[e] = f2bf(qrB[e + 32]);
    }

    const short* Kp = Kf + (size_t)bh * (S_LEN * D_HEAD);
    const short* Vp = Vf + (size_t)bh * (S_LEN * D_HEAD);
    const int lofs = lane * 8;

    const int srcA = ((lane & 15) + ((lane >> 4) & 1) * 32) << 2;
    const int srcB = srcA + (16 << 2);
    const bool glow = (lgrp < 2);

    // ---- pass 1: denominators + PV (unnormalized e) for both subtiles ----
    float lA = 0.f, lB = 0.f;
    f32x4 accA[4] = {}, accB[4] = {};
    for (int j0 = 0; j0 < S_LEN; j0 += 32) {
        const short* kg = Kp + (size_t)(j0 >> 4) * 1024;
        short8 k00 = *reinterpret_cast<const short8*>(kg + lofs);
        short8 k01 = *reinterpret_cast<const short8*>(kg + 512 + lofs);
        short8 k10 = *reinterpret_cast<const short8*>(kg + 1024 + lofs);
        short8 k11 = *reinterpret_cast<const short8*>(kg + 1536 + lofs);
        const short* vg = Vp + (size_t)(j0 >> 5) * 2048;
        short8 bv0 = *reinterpret_cast<const short8*>(vg + lofs);
        short8 bv1 = *reinterpret_cast<const short8*>(vg + 512 + lofs);
        short8 bv2 = *reinterpret_cast<const short8*>(vg + 1024 + lofs);
        short8 bv3 = *reinterpret_cast<const short8*>(vg + 1536 + lofs);

        {
            f32x4 c0 = {0.f, 0.f, 0.f, 0.f};
            f32x4 c1 = {0.f, 0.f, 0.f, 0.f};
            c0 = __builtin_amdgcn_mfma_f32_16x16x32_bf16(k00, qa0A, c0, 0, 0, 0);
            c0 = __builtin_amdgcn_mfma_f32_16x16x32_bf16(k01, qa1A, c0, 0, 0, 0);
            c1 = __builtin_amdgcn_mfma_f32_16x16x32_bf16(k10, qa0A, c1, 0, 0, 0);
            c1 = __builtin_amdgcn_mfma_f32_16x16x32_bf16(k11, qa1A, c1, 0, 0, 0);
            float e0[4], e1[4];
            #pragma unroll
            for (int rr = 0; rr < 4; ++rr) {
                e0[rr] = __expf(c0[rr] * scale);
                e1[rr] = __expf(c1[rr] * scale);
                lA += e0[rr] + e1[rr];
            }
            int w00 = (int)pkbf(e0[0], e0[1]);
            int w01 = (int)pkbf(e0[2], e0[3]);
            int w10 = (int)pkbf(e1[0], e1[1]);
            int w11 = (int)pkbf(e1[2], e1[3]);
            int t0 = __builtin_amdgcn_ds_bpermute(srcA, w00);
            int t1 = __builtin_amdgcn_ds_bpermute(srcA, w01);
            int t2 = __builtin_amdgcn_ds_bpermute(srcB, w00);
            int t3 = __builtin_amdgcn_ds_bpermute(srcB, w01);
            int u0 = __builtin_amdgcn_ds_bpermute(srcA, w10);
            int u1 = __builtin_amdgcn_ds_bpermute(srcA, w11);
            int u2 = __builtin_amdgcn_ds_bpermute(srcB, w10);
            int u3 = __builtin_amdgcn_ds_bpermute(srcB, w11);
            union { short8 s8; int wd[4]; } fr;
            fr.wd[0] = glow ? t0 : u0;
            fr.wd[1] = glow ? t1 : u1;
            fr.wd[2] = glow ? t2 : u2;
            fr.wd[3] = glow ? t3 : u3;
            accA[0] = __builtin_amdgcn_mfma_f32_16x16x32_bf16(fr.s8, bv0, accA[0], 0, 0, 0);
            accA[1] = __builtin_amdgcn_mfma_f32_16x16x32_bf16(fr.s8, bv1, accA[1], 0, 0, 0);
            accA[2] = __builtin_amdgcn_mfma_f32_16x16x32_bf16(fr.s8, bv2, accA[2], 0, 0, 0);
            accA[3] = __builtin_amdgcn_mfma_f32_16x16x32_bf16(fr.s8, bv3, accA[3], 0, 0, 0);
        }
        {
            f32x4 c0 = {0.f, 0.f, 0.f, 0.f};
            f32x4 c1 = {0.f, 0.f, 0.f, 0.f};
            c0 = __builtin_amdgcn_mfma_f32_16x16x32_bf16(k00, qa0B, c0, 0, 0, 0);
            c0 = __builtin_amdgcn_mfma_f32_16x16x32_bf16(k01, qa1B, c0, 0, 0, 0);
            c1 = __builtin_amdgcn_mfma_f32_16x16x32_bf16(k10, qa0B, c1, 0, 0, 0);
            c1 = __builtin_amdgcn_mfma_f32_16x16x32_bf16(k11, qa1B, c1, 0, 0, 0);
            float e0[4], e1[4];
            #pragma unroll
            for (int rr = 0; rr < 4; ++rr) {
                e0[rr] = __expf(c0[rr] * scale);
                e1[rr] = __expf(c1[rr] * scale);
                lB += e0[rr] + e1[rr];
            }
            int w00 = (int)pkbf(e0[0], e0[1]);
            int w01 = (int)pkbf(e0[2], e0[3]);
            int w10 = (int)pkbf(e1[0], e1[1]);
            int w11 = (int)pkbf(e1[2], e1[3]);
            int t0 = __builtin_amdgcn_ds_bpermute(srcA, w00);
            int t1 = __builtin_amdgcn_ds_bpermute(srcA, w01);
            int t2 = __builtin_amdgcn_ds_bpermute(srcB, w00);
            int t3 = __builtin_amdgcn_ds_bpermute(srcB, w01);
            int u0 = __builtin_amdgcn_ds_bpermute(srcA, w10);
            int u1 = __builtin_amdgcn_ds_bpermute(srcA, w11);
            int u2 = __builtin_amdgcn_ds_bpermute(srcB, w10);
            int u3 = __builtin_amdgcn_ds_bpermute(srcB, w11);
            union { short8 s8; int wd[4]; } fr;
            fr.wd[0] = glow ? t0 : u0;
            fr.wd[1] = glow ? t1 : u1;
            fr.wd[2] = glow ? t2 : u2;
            fr.wd[3] = glow ? t3 : u3;
            accB[0] = __builtin_amdgcn_mfma_f32_16x16x32_bf16(fr.s8, bv0, accB[0], 0, 0, 0);
            accB[1] = __builtin_amdgcn_mfma_f32_16x16x32_bf16(fr.s8, bv1, accB[1], 0, 0, 0);
            accB[2] = __builtin_amdgcn_mfma_f32_16x16x32_bf16(fr.s8, bv2, accB[2], 0, 0, 0);
            accB[3] = __builtin_amdgcn_mfma_f32_16x16x32_bf16(fr.s8, bv3, accB[3], 0, 0, 0);
        }
    }
    lA += __shfl_xor(lA, 16);  lA += __shfl_xor(lA, 32);
    lB += __shfl_xor(lB, 16);  lB += __shfl_xor(lB, 32);
    const float rlA = 1.0f / lA;                       // denom for q = qb+lrow
    const float rlB = 1.0f / lB;                       // denom for q = qb+16+lrow

    // ---- epilogue for Out (before the store-heavy pass 2) ----
    {
        float rloA[4], rloB[4];
        #pragma unroll
        for (int rr = 0; rr < 4; ++rr) {
            rloA[rr] = __shfl(rlA, lgrp * 4 + rr);
            rloB[rr] = __shfl(rlB, lgrp * 4 + rr);
        }
        float* obA = Out + ((size_t)bh * S_LEN + qb + lgrp * 4) * D_HEAD + lrow;
        float* obB = obA + (size_t)16 * D_HEAD;
        #pragma unroll
        for (int vt = 0; vt < 4; ++vt) {
            #pragma unroll
            for (int rr = 0; rr < 4; ++rr) {
                obA[(size_t)rr * D_HEAD + vt * 16] = accA[vt][rr] * rloA[rr];
                obB[(size_t)rr * D_HEAD + vt * 16] = accB[vt][rr] * rloB[rr];
            }
        }
    }

    // ---- pass 2: P stream with prefetched K (loads issued BEFORE stores) ----
    char* stgA = (char*)&stage[w][0][0][0];
    char* stgB = (char*)&stage[w][1][0][0];
    const int swz = (lrow & 7) << 4;
    float* Pb = P + (size_t)bh * S_LEN * S_LEN;

    short8 pk00[4], pk01[4], pk10[4], pk11[4];         // next-superstep K frags
    #pragma unroll
    for (int jj = 0; jj < 4; ++jj) {
        const short* kg = Kp + (size_t)((jj * 32) >> 4) * 1024;
        pk00[jj] = *reinterpret_cast<const short8*>(kg + lofs);
        pk01[jj] = *reinterpret_cast<const short8*>(kg + 512 + lofs);
        pk10[jj] = *reinterpret_cast<const short8*>(kg + 1024 + lofs);
        pk11[jj] = *reinterpret_cast<const short8*>(kg + 1536 + lofs);
    }

    for (int sup = 0; sup < S_LEN; sup += SUP) {
        // compute phase: consume prefetched K (oldest in vmcnt FIFO)
        #pragma unroll
        for (int jj = 0; jj < SUP / 32; ++jj) {
            short8 k00 = pk00[jj], k01 = pk01[jj], k10 = pk10[jj], k11 = pk11[jj];
            const int o0 = (lrow * 512 + ((jj * 32 + lgrp * 4) << 2)) ^ swz;
            const int o1 = (lrow * 512 + ((jj * 32 + 16 + lgrp * 4) << 2)) ^ swz;
            {
                f32x4 c0 = {0.f, 0.f, 0.f, 0.f};
                f32x4 c1 = {0.f, 0.f, 0.f, 0.f};
                c0 = __builtin_amdgcn_mfma_f32_16x16x32_bf16(k00, qa0A, c0, 0, 0, 0);
                c0 = __builtin_amdgcn_mfma_f32_16x16x32_bf16(k01, qa1A, c0, 0, 0, 0);
                c1 = __builtin_amdgcn_mfma_f32_16x16x32_bf16(k10, qa0A, c1, 0, 0, 0);
                c1 = __builtin_amdgcn_mfma_f32_16x16x32_bf16(k11, qa1A, c1, 0, 0, 0);
                f32x4 p0, p1;
                #pragma unroll
                for (int rr = 0; rr < 4; ++rr) {
                    p0[rr] = __expf(c0[rr] * scale) * rlA;
                    p1[rr] = __expf(c1[rr] * scale) * rlA;
                }
                *(f32x4*)(stgA + o0) = p0;
                *(f32x4*)(stgA + o1) = p1;
            }
            {
                f32x4 c0 = {0.f, 0.f, 0.f, 0.f};
                f32x4 c1 = {0.f, 0.f, 0.f, 0.f};
                c0 = __builtin_amdgcn_mfma_f32_16x16x32_bf16(k00, qa0B, c0, 0, 0, 0);
                c0 = __builtin_amdgcn_mfma_f32_16x16x32_bf16(k01, qa1B, c0, 0, 0, 0);
                c1 = __builtin_amdgcn_mfma_f32_16x16x32_bf16(k10, qa0B, c1, 0, 0, 0);
                c1 = __builtin_amdgcn_mfma_f32_16x16x32_bf16(k11, qa1B, c1, 0, 0, 0);
                f32x4 p0, p1;
                #pragma unroll
                for (int rr = 0; rr < 4; ++rr) {
                    p0[rr] = __expf(c0[rr] * scale) * rlB;
                    p1[rr] = __expf(c1[rr] * scale) * rlB;
                }
                *(f32x4*)(stgB + o0) = p0;
                *(f32x4*)(stgB + o1) = p1;
            }
        }

        asm volatile("s_waitcnt lgkmcnt(0)" ::: "memory");

        // prefetch next superstep's K BEFORE the store burst (counted-vmcnt
        // decoupling: these loads are older than the stores below)
        {
            const int nsup = (sup + SUP < S_LEN) ? (sup + SUP) : 0;
            #pragma unroll
            for (int jj = 0; jj < 4; ++jj) {
                const short* kg = Kp + (size_t)((nsup + jj * 32) >> 4) * 1024;
                pk00[jj] = *reinterpret_cast<const short8*>(kg + lofs);
                pk01[jj] = *reinterpret_cast<const short8*>(kg + 512 + lofs);
                pk10[jj] = *reinterpret_cast<const short8*>(kg + 1024 + lofs);
                pk11[jj] = *reinterpret_cast<const short8*>(kg + 1536 + lofs);
            }
        }
        __builtin_amdgcn_sched_barrier(0);             // pin: loads stay above stores

        // burst store: 2 rows x 512B per instruction, nontemporal (P is
        // never re-read; keep the 537MB stream out of L2 so K/V stay resident)
        #pragma unroll
        for (int rb = 0; rb < 8; ++rb) {
            const int r = rb * 2 + (lane >> 5);
            const int c = lane & 31;
            f32x4 pv = *(const f32x4*)(stgA + ((r * 512 + c * 16) ^ ((r & 7) << 4)));
            __builtin_nontemporal_store(pv,
                (f32x4*)(Pb + (size_t)(qb + r) * S_LEN + sup + c * 4));
        }
        #pragma unroll
        for (int rb = 0; rb < 8; ++rb) {
            const int r = rb * 2 + (lane >> 5);
            const int c = lane & 31;
            f32x4 pv = *(const f32x4*)(stgB + ((r * 512 + c * 16) ^ ((r & 7) << 4)));
            __builtin_nontemporal_store(pv,
                (f32x4*)(Pb + (size_t)(qb + 16 + r) * S_LEN + sup + c * 4));
        }
        asm volatile("s_waitcnt lgkmcnt(0)" ::: "memory");
    }
}

extern "C" void kernel_launch(void* const* d_in, const int* in_sizes, int n_in,
                              void* d_out, int out_size, void* d_ws, size_t ws_size,
                              hipStream_t stream) {
    const float* Q = (const float*)d_in[0];
    const float* K = (const float*)d_in[1];
    const float* V = (const float*)d_in[2];
    float* Out = (float*)d_out;
    float* P = Out + (size_t)NELEM;                    // outputs concatenated flat
    short* Kf = (short*)d_ws;                          // 8.4 MB
    short* Vf = Kf + (size_t)NELEM;                    // 8.4 MB (needs ws >= 16.8 MB)

    convert_kf_kernel<<<NELEM / (256 * 8), 256, 0, stream>>>(K, Kf);
    transpose_vf_kernel<<<dim3(S_LEN / 64, NBH), 256, 0, stream>>>(V, Vf);
    attn_kernel<<<dim3(S_LEN / 128, NBH), 256, 0, stream>>>(Q, Kf, Vf, Out, P);
}